// Round 2
// baseline (766.712 us; speedup 1.0000x reference)
//
#include <hip/hip_runtime.h>
#include <math.h>

#define N_CAPS 64
#define IN_CAPS 4096
#define CAP_DIM 32
#define IN_DIM 16
#define EPS 1e-7f

typedef float f32x4 __attribute__((ext_vector_type(4)));

// ws layout (floats):
//   u:     [0, 8388608)                      = 32 MB  (64*4096*32)
//   reduction area at RED_BASE:
//     s_acc0(2048) s_acc1(2048) s_acc2(2048) Z1(64) Z2(64) V(2048)
// total ws needed: (8388608 + 8320)*4 bytes ~= 33.6 MB
static constexpr size_t U_ELEMS   = (size_t)N_CAPS * IN_CAPS * CAP_DIM; // 8388608
static constexpr size_t RED_BASE  = U_ELEMS;
static constexpr size_t OFF_SACC0 = 0;
static constexpr size_t OFF_SACC1 = 2048;
static constexpr size_t OFF_SACC2 = 4096;
static constexpr size_t OFF_Z1    = 6144;
static constexpr size_t OFF_Z2    = 6208;
static constexpr size_t OFF_V     = 6272;
static constexpr int    RED_TOTAL = 6272 + 2048; // 8320 floats

// ---------------------------------------------------------------------------
// Zero the reduction scratch (harness poisons ws with 0xAA before every call).
__global__ __launch_bounds__(256) void init_kernel(float* __restrict__ red) {
    for (int j = threadIdx.x; j < RED_TOTAL; j += 256) red[j] = 0.0f;
}

// ---------------------------------------------------------------------------
// u[n,i,d] = dot(W[n,i,d,0:16], x[i,0:16]).  One thread per output element.
// Each thread reads 64 contiguous bytes of W (4x float4, nontemporal: W is
// streamed once; keep u resident in L2/L3 for the routing passes).
// Block = 256 threads = 8 consecutive i's x 32 d's (one n). x staged in LDS.
__global__ __launch_bounds__(256) void compute_u_kernel(
        const float* __restrict__ W, const float* __restrict__ x,
        float* __restrict__ u) {
    __shared__ __align__(16) float xs[8 * IN_DIM]; // 8 i's staged
    const int tid = threadIdx.x;
    const size_t e0 = (size_t)blockIdx.x * 256;
    const size_t e  = e0 + tid;
    const int i0 = (int)((e0 >> 5) & (IN_CAPS - 1)); // first i of this block
    if (tid < 8 * IN_DIM) xs[tid] = x[(size_t)i0 * IN_DIM + tid];
    __syncthreads();

    const f32x4* wp = (const f32x4*)W + e * 4;
    f32x4 w0 = __builtin_nontemporal_load(wp + 0);
    f32x4 w1 = __builtin_nontemporal_load(wp + 1);
    f32x4 w2 = __builtin_nontemporal_load(wp + 2);
    f32x4 w3 = __builtin_nontemporal_load(wp + 3);

    const f32x4* xv = (const f32x4*)(xs + (tid >> 5) * IN_DIM);
    f32x4 x0 = xv[0], x1 = xv[1], x2 = xv[2], x3 = xv[3];

    float acc = w0.x * x0.x + w0.y * x0.y + w0.z * x0.z + w0.w * x0.w
              + w1.x * x1.x + w1.y * x1.y + w1.z * x1.z + w1.w * x1.w
              + w2.x * x2.x + w2.y * x2.y + w2.z * x2.z + w2.w * x2.w
              + w3.x * x3.x + w3.y * x3.y + w3.z * x3.z + w3.w * x3.w;
    u[e] = acc;
}

// ---------------------------------------------------------------------------
// Iter-1 s accumulation: s_acc0[n,d] += sum_i u[n,i,d]  (c is uniform 1/4096,
// scaling applied in squash).  Grid = 64 n * 4 chunks; block 256 = (ii,d).
__global__ __launch_bounds__(256) void sum_u_kernel(
        const float* __restrict__ u, float* __restrict__ s_acc) {
    __shared__ float red[256];
    const int n = blockIdx.x >> 2, chunk = blockIdx.x & 3;
    const int tid = threadIdx.x, ii = tid >> 5, d = tid & 31;
    const size_t base = ((size_t)n * IN_CAPS + (size_t)chunk * 1024) * CAP_DIM;
    float acc = 0.0f;
    for (int step = 0; step < 128; ++step)
        acc += u[base + (size_t)(step * 8 + ii) * CAP_DIM + d];
    red[tid] = acc; __syncthreads();
    for (int s = 128; s >= 32; s >>= 1) {
        if (tid < s) red[tid] += red[tid + s];
        __syncthreads();
    }
    if (tid < 32) atomicAdd(&s_acc[n * CAP_DIM + tid], red[tid]);
}

// ---------------------------------------------------------------------------
// Routing pass for iters 2,3: per (n, i-chunk) block computes
//   t = dot(u[n,i,:], V[n,:]);  w = exp(t)   (logits are tiny: no max needed)
//   Z[n]       += sum_i w
//   s_acc[n,d] += sum_i w * u[n,i,d]
__global__ __launch_bounds__(256) void route_kernel(
        const float* __restrict__ u, const float* __restrict__ V,
        float* __restrict__ s_acc, float* __restrict__ Z) {
    __shared__ __align__(16) float vs[CAP_DIM];
    __shared__ float wbuf[256];
    __shared__ float red[256];
    const int n = blockIdx.x >> 2, chunk = blockIdx.x & 3;
    const int tid = threadIdx.x, ii = tid >> 5, d = tid & 31;
    if (tid < CAP_DIM) vs[tid] = V[n * CAP_DIM + tid];
    __syncthreads();

    const size_t ubase = (size_t)n * IN_CAPS * CAP_DIM;
    float zacc = 0.0f, sacc = 0.0f;

    for (int c = 0; c < 4; ++c) {
        const int ibase = chunk * 1024 + c * 256;
        // phase A: one i per thread, 128B contiguous read of u[n,i,:]
        {
            const f32x4* up = (const f32x4*)(u + ubase + (size_t)(ibase + tid) * CAP_DIM);
            const f32x4* vv = (const f32x4*)vs;
            float t = 0.0f;
            for (int q = 0; q < 8; ++q) {
                f32x4 a = up[q], b = vv[q];
                t += a.x * b.x + a.y * b.y + a.z * b.z + a.w * b.w;
            }
            float w = expf(t);
            wbuf[tid] = w;
            zacc += w;
        }
        __syncthreads();
        // phase B: (ii,d) layout, coalesced re-read (L1/L2-hot)
        {
            const size_t off = ubase + (size_t)ibase * CAP_DIM;
            for (int k = 0; k < 32; ++k) {
                const int li = k * 8 + ii;
                sacc += wbuf[li] * u[off + (size_t)li * CAP_DIM + d];
            }
        }
        __syncthreads();
    }

    red[tid] = sacc; __syncthreads();
    for (int s = 128; s >= 32; s >>= 1) {
        if (tid < s) red[tid] += red[tid + s];
        __syncthreads();
    }
    if (tid < 32) atomicAdd(&s_acc[n * CAP_DIM + tid], red[tid]);
    __syncthreads();
    red[tid] = zacc; __syncthreads();
    for (int s = 128; s >= 1; s >>= 1) {
        if (tid < s) red[tid] += red[tid + s];
        __syncthreads();
    }
    if (tid == 0) atomicAdd(&Z[n], red[0]);
}

// ---------------------------------------------------------------------------
// Global squash: s = s_acc * (Z ? 1/Z[n] : 1/4096);  sq = sum_ALL(s*s);
// v = s * sq/(1+sq)/(sqrt(sq)+EPS);  V += v;  optionally write v to out.
// Single block, 2048 elements.
__global__ __launch_bounds__(256) void squash_kernel(
        const float* __restrict__ s_acc, const float* __restrict__ Z,
        float* __restrict__ V, float* __restrict__ out) {
    __shared__ __align__(16) float sv[N_CAPS * CAP_DIM];
    __shared__ float red[256];
    __shared__ float factor;
    const int tid = threadIdx.x;
    float psum = 0.0f;
    for (int k = 0; k < 8; ++k) {
        const int j = tid + 256 * k;
        const float scale = Z ? (1.0f / Z[j >> 5]) : (1.0f / (float)IN_CAPS);
        const float s = s_acc[j] * scale;
        sv[j] = s;
        psum += s * s;
    }
    red[tid] = psum; __syncthreads();
    for (int s = 128; s >= 1; s >>= 1) {
        if (tid < s) red[tid] += red[tid + s];
        __syncthreads();
    }
    if (tid == 0) {
        const float sq = red[0];
        factor = sq / (1.0f + sq) / (sqrtf(sq) + EPS);
    }
    __syncthreads();
    for (int k = 0; k < 8; ++k) {
        const int j = tid + 256 * k;
        const float v = sv[j] * factor;
        if (V)   V[j] += v;
        if (out) out[j] = v;
    }
}

// ---------------------------------------------------------------------------
extern "C" void kernel_launch(void* const* d_in, const int* in_sizes, int n_in,
                              void* d_out, int out_size, void* d_ws, size_t ws_size,
                              hipStream_t stream) {
    const float* x = (const float*)d_in[0];  // (4096, 16, 1)
    const float* W = (const float*)d_in[1];  // (64, 4096, 32, 16)
    float* out = (float*)d_out;              // (64, 32, 1)
    float* ws  = (float*)d_ws;

    float* u     = ws;
    float* redb  = ws + RED_BASE;
    float* sacc0 = redb + OFF_SACC0;
    float* sacc1 = redb + OFF_SACC1;
    float* sacc2 = redb + OFF_SACC2;
    float* Z1    = redb + OFF_Z1;
    float* Z2    = redb + OFF_Z2;
    float* V     = redb + OFF_V;

    init_kernel<<<1, 256, 0, stream>>>(redb);
    compute_u_kernel<<<(int)(U_ELEMS / 256), 256, 0, stream>>>(W, x, u);

    // iter 1: uniform c
    sum_u_kernel<<<N_CAPS * 4, 256, 0, stream>>>(u, sacc0);
    squash_kernel<<<1, 256, 0, stream>>>(sacc0, nullptr, V, nullptr);
    // iter 2
    route_kernel<<<N_CAPS * 4, 256, 0, stream>>>(u, V, sacc1, Z1);
    squash_kernel<<<1, 256, 0, stream>>>(sacc1, Z1, V, nullptr);
    // iter 3 (v written to output; V update not needed)
    route_kernel<<<N_CAPS * 4, 256, 0, stream>>>(u, V, sacc2, Z2);
    squash_kernel<<<1, 256, 0, stream>>>(sacc2, Z2, nullptr, out);
}

// Round 3
// 723.831 us; speedup vs baseline: 1.0592x; 1.0592x over previous
//
#include <hip/hip_runtime.h>
#include <math.h>

#define N_CAPS 64
#define IN_CAPS 4096
#define CAP_DIM 32
#define IN_DIM 16
#define EPS 1e-7f

typedef float f32x4 __attribute__((ext_vector_type(4)));

// ws layout (floats):
//   u:     [0, 8388608)                      = 32 MB  (64*4096*32)
//   reduction area at RED_BASE:
//     s_acc0(2048) s_acc1(2048) s_acc2(2048) Z1(64) Z2(64) V(2048)
static constexpr size_t U_ELEMS   = (size_t)N_CAPS * IN_CAPS * CAP_DIM; // 8388608
static constexpr size_t RED_BASE  = U_ELEMS;
static constexpr size_t OFF_SACC0 = 0;
static constexpr size_t OFF_SACC1 = 2048;
static constexpr size_t OFF_SACC2 = 4096;
static constexpr size_t OFF_Z1    = 6144;
static constexpr size_t OFF_Z2    = 6208;
static constexpr size_t OFF_V     = 6272;
static constexpr int    RED_TOTAL = 6272 + 2048; // 8320 floats

// ---------------------------------------------------------------------------
// Zero the reduction scratch (harness poisons ws with 0xAA before every call).
__global__ __launch_bounds__(256) void init_kernel(float* __restrict__ red) {
    for (int j = threadIdx.x; j < RED_TOTAL; j += 256) red[j] = 0.0f;
}

// ---------------------------------------------------------------------------
// u[n,i,d] = dot(W[n,i,d,0:16], x[i,0:16]).
// Coalesced scheme: each wave owns 64 consecutive output elements = 4 KB of W.
// Round r: lane L loads float4 #(r*64+L) of the wave's W chunk (lane-contiguous
// 1 KB per instruction, nontemporal: every line consumed by exactly one
// instruction, and W must not evict u from L2/L3). Lane L holds quarter (L&3)
// of local element r*16+(L>>2); dot4 against the x-quarter from LDS, then
// shfl_xor(1)+shfl_xor(2) butterfly sums the 4 quarter-dots within the quad.
// After 4 rounds lane L keeps res[L&3] = element (L&3)*16+(L>>2): the wave's
// store is a permutation of 64 consecutive floats (fully coalesced).
__global__ __launch_bounds__(256) void compute_u_kernel(
        const float* __restrict__ W, const float* __restrict__ x,
        float* __restrict__ u) {
    __shared__ __align__(16) float xs[8 * IN_DIM]; // 8 i's staged
    const int tid = threadIdx.x;
    const size_t e0 = (size_t)blockIdx.x * 256;
    const int i0 = (int)((e0 >> 5) & (IN_CAPS - 1)); // first i of this block
    if (tid < 8 * IN_DIM) xs[tid] = x[(size_t)i0 * IN_DIM + tid];
    __syncthreads();

    const int w = tid >> 6, L = tid & 63, q = L & 3, k = L >> 2;
    const size_t ebase = e0 + (size_t)w * 64;       // wave's first element
    const f32x4* wp = (const f32x4*)W + ebase * 4;  // 4 float4 per element

    float res[4];
    #pragma unroll
    for (int r = 0; r < 4; ++r) {
        f32x4 wv = __builtin_nontemporal_load(wp + r * 64 + L);
        const int le = w * 64 + r * 16 + k;         // local element index
        const f32x4 xv = *(const f32x4*)(xs + (le >> 5) * IN_DIM + q * 4);
        float p = wv.x * xv.x + wv.y * xv.y + wv.z * xv.z + wv.w * xv.w;
        p += __shfl_xor(p, 1, 64);
        p += __shfl_xor(p, 2, 64);
        res[r] = p;
    }
    const float outv = q == 0 ? res[0] : q == 1 ? res[1] : q == 2 ? res[2] : res[3];
    u[ebase + q * 16 + k] = outv;
}

// ---------------------------------------------------------------------------
// Iter-1 s accumulation: s_acc0[n,d] += sum_i u[n,i,d]  (c is uniform 1/4096,
// scaling applied in squash).  Grid = 64 n * 4 chunks; block 256 = (ii,d).
__global__ __launch_bounds__(256) void sum_u_kernel(
        const float* __restrict__ u, float* __restrict__ s_acc) {
    __shared__ float red[256];
    const int n = blockIdx.x >> 2, chunk = blockIdx.x & 3;
    const int tid = threadIdx.x, ii = tid >> 5, d = tid & 31;
    const size_t base = ((size_t)n * IN_CAPS + (size_t)chunk * 1024) * CAP_DIM;
    float acc = 0.0f;
    for (int step = 0; step < 128; ++step)
        acc += u[base + (size_t)(step * 8 + ii) * CAP_DIM + d];
    red[tid] = acc; __syncthreads();
    for (int s = 128; s >= 32; s >>= 1) {
        if (tid < s) red[tid] += red[tid + s];
        __syncthreads();
    }
    if (tid < 32) atomicAdd(&s_acc[n * CAP_DIM + tid], red[tid]);
}

// ---------------------------------------------------------------------------
// Routing pass for iters 2,3: per (n, i-chunk) block computes
//   t = dot(u[n,i,:], V[n,:]);  w = exp(t)   (logits are tiny: no max needed)
//   Z[n]       += sum_i w
//   s_acc[n,d] += sum_i w * u[n,i,d]
__global__ __launch_bounds__(256) void route_kernel(
        const float* __restrict__ u, const float* __restrict__ V,
        float* __restrict__ s_acc, float* __restrict__ Z) {
    __shared__ __align__(16) float vs[CAP_DIM];
    __shared__ float wbuf[256];
    __shared__ float red[256];
    const int n = blockIdx.x >> 2, chunk = blockIdx.x & 3;
    const int tid = threadIdx.x, ii = tid >> 5, d = tid & 31;
    if (tid < CAP_DIM) vs[tid] = V[n * CAP_DIM + tid];
    __syncthreads();

    const size_t ubase = (size_t)n * IN_CAPS * CAP_DIM;
    float zacc = 0.0f, sacc = 0.0f;

    for (int c = 0; c < 4; ++c) {
        const int ibase = chunk * 1024 + c * 256;
        // phase A: one i per thread, 128B contiguous read of u[n,i,:]
        {
            const f32x4* up = (const f32x4*)(u + ubase + (size_t)(ibase + tid) * CAP_DIM);
            const f32x4* vv = (const f32x4*)vs;
            float t = 0.0f;
            for (int q = 0; q < 8; ++q) {
                f32x4 a = up[q], b = vv[q];
                t += a.x * b.x + a.y * b.y + a.z * b.z + a.w * b.w;
            }
            float w = expf(t);
            wbuf[tid] = w;
            zacc += w;
        }
        __syncthreads();
        // phase B: (ii,d) layout, coalesced re-read (L1/L2-hot)
        {
            const size_t off = ubase + (size_t)ibase * CAP_DIM;
            for (int k = 0; k < 32; ++k) {
                const int li = k * 8 + ii;
                sacc += wbuf[li] * u[off + (size_t)li * CAP_DIM + d];
            }
        }
        __syncthreads();
    }

    red[tid] = sacc; __syncthreads();
    for (int s = 128; s >= 32; s >>= 1) {
        if (tid < s) red[tid] += red[tid + s];
        __syncthreads();
    }
    if (tid < 32) atomicAdd(&s_acc[n * CAP_DIM + tid], red[tid]);
    __syncthreads();
    red[tid] = zacc; __syncthreads();
    for (int s = 128; s >= 1; s >>= 1) {
        if (tid < s) red[tid] += red[tid + s];
        __syncthreads();
    }
    if (tid == 0) atomicAdd(&Z[n], red[0]);
}

// ---------------------------------------------------------------------------
// Global squash: s = s_acc * (Z ? 1/Z[n] : 1/4096);  sq = sum_ALL(s*s);
// v = s * sq/(1+sq)/(sqrt(sq)+EPS);  V += v;  optionally write v to out.
// Single block, 2048 elements.
__global__ __launch_bounds__(256) void squash_kernel(
        const float* __restrict__ s_acc, const float* __restrict__ Z,
        float* __restrict__ V, float* __restrict__ out) {
    __shared__ __align__(16) float sv[N_CAPS * CAP_DIM];
    __shared__ float red[256];
    __shared__ float factor;
    const int tid = threadIdx.x;
    float psum = 0.0f;
    for (int k = 0; k < 8; ++k) {
        const int j = tid + 256 * k;
        const float scale = Z ? (1.0f / Z[j >> 5]) : (1.0f / (float)IN_CAPS);
        const float s = s_acc[j] * scale;
        sv[j] = s;
        psum += s * s;
    }
    red[tid] = psum; __syncthreads();
    for (int s = 128; s >= 1; s >>= 1) {
        if (tid < s) red[tid] += red[tid + s];
        __syncthreads();
    }
    if (tid == 0) {
        const float sq = red[0];
        factor = sq / (1.0f + sq) / (sqrtf(sq) + EPS);
    }
    __syncthreads();
    for (int k = 0; k < 8; ++k) {
        const int j = tid + 256 * k;
        const float v = sv[j] * factor;
        if (V)   V[j] += v;
        if (out) out[j] = v;
    }
}

// ---------------------------------------------------------------------------
extern "C" void kernel_launch(void* const* d_in, const int* in_sizes, int n_in,
                              void* d_out, int out_size, void* d_ws, size_t ws_size,
                              hipStream_t stream) {
    const float* x = (const float*)d_in[0];  // (4096, 16, 1)
    const float* W = (const float*)d_in[1];  // (64, 4096, 32, 16)
    float* out = (float*)d_out;              // (64, 32, 1)
    float* ws  = (float*)d_ws;

    float* u     = ws;
    float* redb  = ws + RED_BASE;
    float* sacc0 = redb + OFF_SACC0;
    float* sacc1 = redb + OFF_SACC1;
    float* sacc2 = redb + OFF_SACC2;
    float* Z1    = redb + OFF_Z1;
    float* Z2    = redb + OFF_Z2;
    float* V     = redb + OFF_V;

    init_kernel<<<1, 256, 0, stream>>>(redb);
    compute_u_kernel<<<(int)(U_ELEMS / 256), 256, 0, stream>>>(W, x, u);

    // iter 1: uniform c
    sum_u_kernel<<<N_CAPS * 4, 256, 0, stream>>>(u, sacc0);
    squash_kernel<<<1, 256, 0, stream>>>(sacc0, nullptr, V, nullptr);
    // iter 2
    route_kernel<<<N_CAPS * 4, 256, 0, stream>>>(u, V, sacc1, Z1);
    squash_kernel<<<1, 256, 0, stream>>>(sacc1, Z1, V, nullptr);
    // iter 3 (v written to output; V update not needed)
    route_kernel<<<N_CAPS * 4, 256, 0, stream>>>(u, V, sacc2, Z2);
    squash_kernel<<<1, 256, 0, stream>>>(sacc2, Z2, nullptr, out);
}